// Round 2
// baseline (17203.630 us; speedup 1.0000x reference)
//
#include <hip/hip_runtime.h>
#include <hip/hip_bf16.h>
#include <stdint.h>

#define HDIM 1024
#define GDIM 5120
#define NWG_SER 128
#define RPW 10  // rows per wave in serial kernel (40 rows/WG / 4 waves)

typedef __attribute__((ext_vector_type(8))) short v8s;
typedef __attribute__((ext_vector_type(4))) float v4f;

// ---------------- workspace layout (bytes) ----------------
constexpr long long PRE_OFF   = 0;                              // f32 [2048][5120] gate pre-sums for reduces
constexpr long long LEAFG_OFF = PRE_OFF   + 2048LL * 5120 * 4;  // f32 [2048][5120] leaf gates
constexpr long long DUMP_OFF  = LEAFG_OFF + 2048LL * 5120 * 4;  // f32 [8192] scratch dump row
constexpr long long XSBF_OFF  = DUMP_OFF  + 8192LL * 4;         // bf16 [4096][1024]
constexpr long long WIH_OFF   = XSBF_OFF  + 4096LL * 1024 * 2;  // bf16 [5120][1024]
constexpr long long WLHH_OFF  = WIH_OFF   + 5120LL * 1024 * 2;
constexpr long long WRHH_OFF  = WLHH_OFF  + 5120LL * 1024 * 2;
constexpr long long HBF_OFF   = WRHH_OFF  + 5120LL * 1024 * 2;  // bf16 [4096][1024] per-node h (leaves; GEMM input)
constexpr long long B3_OFF    = HBF_OFF   + 4096LL * 1024 * 2;  // f32 [5120]
constexpr long long PLAN_OFF  = B3_OFF    + 5120LL * 4;         // int [24576]
constexpr long long BAR_OFF   = PLAN_OFF  + 24576LL * 4;        // int [1024] (zeroed each launch)
// total ~126.3 MiB

// plan array offsets (int units)
constexpr int P_TRED = 0, P_LNODE = 2048, P_RNODE = 4096, P_FLAGS = 6144,
              P_TLEAF = 8192, P_DEST1 = 10240, P_NODER = 14336, P_DESTR = 16384,
              P_NODEL = 18432, P_DESTL = 20480, P_CNT = 22528;
// counts: [0]=nred, [1]=activeR rows, [2]=activeL rows, [3]=n_nodes (G1 active rows)

// f32-element bases inside ws
constexpr int PRE_E   = 0;
constexpr int LEAFG_E = (int)(LEAFG_OFF / 4);
constexpr int DUMP_E  = (int)(DUMP_OFF / 4);

static __device__ __forceinline__ float sigf(float x) { return 1.0f / (1.0f + __expf(-x)); }
static __device__ __forceinline__ float tanh_f(float x) {
  if (x > 15.0f) return 1.0f;
  if (x < -15.0f) return -1.0f;
  float e = __expf(2.0f * x);
  return (e - 1.0f) / (e + 1.0f);
}
static __device__ __forceinline__ unsigned short f2bf(float x) {
  __hip_bfloat16 h = __float2bfloat16(x);
  union { __hip_bfloat16 h; unsigned short u; } cv;
  cv.h = h;
  return cv.u;
}

// ---------------- plan: simulate the stack, build scatter lists ----------------
__global__ void plan_kernel(const int* __restrict__ ops, int n_nodes, int* __restrict__ plan) {
  __shared__ int sops[4096];
  for (int i = threadIdx.x; i < n_nodes; i += 256) sops[i] = ops[i];
  __syncthreads();
  if (threadIdx.x != 0) return;
  int stack[4] = {0, 0, 0, 0};
  int ptr = 0, nred = 0, nleaf = 0, nR = 0, nL = 0;
  for (int t = 0; t < n_nodes; ++t) {
    int op = sops[t];
    if (op == 1) {
      int ridx = min(max(ptr - 1, 0), 3);
      int lidx = min(max(ptr - 2, 0), 3);
      int ln = stack[lidx], rn = stack[ridx];
      int r = nred++;
      plan[P_TRED + r] = t;
      plan[P_LNODE + r] = ln;
      plan[P_RNODE + r] = rn;
      int lred = (sops[ln] == 1) ? 1 : 0;
      int rred = (sops[rn] == 1) ? 2 : 0;
      plan[P_FLAGS + r] = lred | rred;
      plan[P_DEST1 + t] = PRE_E + r * GDIM;
      if (!rred) { plan[P_NODER + nR] = rn; plan[P_DESTR + nR] = PRE_E + r * GDIM; nR++; }
      if (!lred) { plan[P_NODEL + nL] = ln; plan[P_DESTL + nL] = PRE_E + r * GDIM; nL++; }
      int pos = ptr - 2;
      stack[min(max(pos, 0), 3)] = t;
      ptr = pos + 1;
    } else {
      int li = nleaf++;
      plan[P_TLEAF + li] = t;
      plan[P_DEST1 + t] = LEAFG_E + li * GDIM;
      stack[min(max(ptr, 0), 3)] = t;
      ptr = ptr + 1;
    }
  }
  for (int i = n_nodes; i < 4096; ++i) plan[P_DEST1 + i] = DUMP_E;
  for (int i = nR; i < 2048; ++i) { plan[P_NODER + i] = 0; plan[P_DESTR + i] = DUMP_E; }
  for (int i = nL; i < 2048; ++i) { plan[P_NODEL + i] = 0; plan[P_DESTL + i] = DUMP_E; }
  plan[P_CNT + 0] = nred;
  plan[P_CNT + 1] = nR;
  plan[P_CNT + 2] = nL;
  plan[P_CNT + 3] = n_nodes;
}

// ---------------- f32 -> bf16 convert (zero-pads beyond nsrc) ----------------
__global__ void cvt_bf16_kernel(const float* __restrict__ src, unsigned short* __restrict__ dst,
                                int ntotal, int nsrc) {
  int i = (blockIdx.x * 256 + threadIdx.x) * 4;
  if (i >= ntotal) return;
  float4 v = make_float4(0.f, 0.f, 0.f, 0.f);
  if (i < nsrc) v = *(const float4*)(src + i);
  ushort4 o;
  o.x = f2bf(v.x); o.y = f2bf(v.y); o.z = f2bf(v.z); o.w = f2bf(v.w);
  *(ushort4*)(dst + i) = o;
}

__global__ void b3_kernel(const float* __restrict__ a, const float* __restrict__ b,
                          const float* __restrict__ c, float* __restrict__ o) {
  int i = blockIdx.x * 256 + threadIdx.x;
  if (i < GDIM) o[i] = a[i] + b[i] + c[i];
}

// ---------------- NT MFMA GEMM with per-row scatter destinations ----------------
// C[row][col] = sum_k A[row][k] * B[col][k]; A rows optionally gathered by index.
// ACCUM=0: dst = v + b3[col]; ACCUM=1: dst += v.
template <int GATHER, int ACCUM>
__global__ __launch_bounds__(256, 1) void gemm_bt(
    const unsigned short* __restrict__ A, const unsigned short* __restrict__ B,
    const int* __restrict__ gidx, const int* __restrict__ dest,
    float* __restrict__ wsf, const float* __restrict__ b3,
    const int* __restrict__ activeRows) {
  if ((int)blockIdx.x * 128 >= *activeRows) return;
  __shared__ unsigned short As[128 * 32];
  __shared__ unsigned short Bs[128 * 32];
  const int tid = threadIdx.x;
  const int w = tid >> 6, l = tid & 63;
  const int tm = blockIdx.x, tn = blockIdx.y;
  const int q0 = w * 2, q1 = w * 2 + 1;
  const int r0 = q0 * 16 + (l >> 2), r1 = q1 * 16 + (l >> 2);
  const int ck = (l & 3) * 8;  // ushort offset within the 32-wide k slice
  int ga0 = tm * 128 + r0, ga1 = tm * 128 + r1;
  if (GATHER) { ga0 = gidx[ga0]; ga1 = gidx[ga1]; }
  const unsigned short* ap0 = A + (long long)ga0 * HDIM + ck;
  const unsigned short* ap1 = A + (long long)ga1 * HDIM + ck;
  const unsigned short* bp0 = B + (long long)(tn * 128 + r0) * HDIM + ck;
  const unsigned short* bp1 = B + (long long)(tn * 128 + r1) * HDIM + ck;
  uint4* asd0 = (uint4*)(As + q0 * 512) + l;
  uint4* asd1 = (uint4*)(As + q1 * 512) + l;
  uint4* bsd0 = (uint4*)(Bs + q0 * 512) + l;
  uint4* bsd1 = (uint4*)(Bs + q1 * 512) + l;
  const int wr = w >> 1, wc = w & 1;
  const int lrow = l & 15, lq = l >> 4;
  const unsigned short* Ard = As + (wr * 64 + lrow) * 32 + lq * 8;
  const unsigned short* Brd = Bs + (wc * 64 + lrow) * 32 + lq * 8;
  v4f acc[4][4];
#pragma unroll
  for (int m = 0; m < 4; ++m)
#pragma unroll
    for (int n = 0; n < 4; ++n) acc[m][n] = (v4f){0.f, 0.f, 0.f, 0.f};
  for (int kb = 0; kb < 32; ++kb) {
    const int ko = kb * 32;
    uint4 a0 = *(const uint4*)(ap0 + ko);
    uint4 a1 = *(const uint4*)(ap1 + ko);
    uint4 b0 = *(const uint4*)(bp0 + ko);
    uint4 b1 = *(const uint4*)(bp1 + ko);
    __syncthreads();
    *asd0 = a0; *asd1 = a1; *bsd0 = b0; *bsd1 = b1;
    __syncthreads();
    v8s af[4], bfr[4];
#pragma unroll
    for (int m = 0; m < 4; ++m) af[m] = *(const v8s*)(Ard + m * 512);
#pragma unroll
    for (int n = 0; n < 4; ++n) bfr[n] = *(const v8s*)(Brd + n * 512);
#pragma unroll
    for (int m = 0; m < 4; ++m)
#pragma unroll
      for (int n = 0; n < 4; ++n)
        acc[m][n] = __builtin_amdgcn_mfma_f32_16x16x32_bf16(af[m], bfr[n], acc[m][n], 0, 0, 0);
  }
#pragma unroll
  for (int m = 0; m < 4; ++m) {
#pragma unroll
    for (int jj = 0; jj < 4; ++jj) {
      const int arow = tm * 128 + wr * 64 + m * 16 + lq * 4 + jj;
      const int doff = dest[arow];
#pragma unroll
      for (int n = 0; n < 4; ++n) {
        const int col = tn * 128 + wc * 64 + n * 16 + lrow;
        float v = acc[m][n][jj];
        if (ACCUM) wsf[doff + col] += v;
        else wsf[doff + col] = v + b3[col];
      }
    }
  }
}

// ---------------- leaf (shift) cell: gates -> h,c with zero hidden state ----------------
__global__ void leaf_cell(const float* __restrict__ leafg, const int* __restrict__ plan,
                          float* __restrict__ hs, float* __restrict__ cs,
                          unsigned short* __restrict__ hbf) {
  const int li = blockIdx.x;
  const int j = threadIdx.x * 4;
  const float* row = leafg + (long long)li * GDIM;
  float4 gi = *(const float4*)(row + j);
  float4 gg = *(const float4*)(row + 3 * HDIM + j);
  float4 go = *(const float4*)(row + 4 * HDIM + j);
  const int t = plan[P_TLEAF + li];
  float4 yc, yh;
  yc.x = sigf(gi.x) * tanh_f(gg.x); yc.y = sigf(gi.y) * tanh_f(gg.y);
  yc.z = sigf(gi.z) * tanh_f(gg.z); yc.w = sigf(gi.w) * tanh_f(gg.w);
  yh.x = sigf(go.x) * tanh_f(yc.x); yh.y = sigf(go.y) * tanh_f(yc.y);
  yh.z = sigf(go.z) * tanh_f(yc.z); yh.w = sigf(go.w) * tanh_f(yc.w);
  *(float4*)(hs + (long long)t * HDIM + j) = yh;
  *(float4*)(cs + (long long)t * HDIM + j) = yc;
  ushort4 hb;
  hb.x = f2bf(yh.x); hb.y = f2bf(yh.y); hb.z = f2bf(yh.z); hb.w = f2bf(yh.w);
  *(ushort4*)(hbf + (long long)t * HDIM + j) = hb;
}

// ---------------- serial reduce chain: persistent 128-WG kernel, full f32 ----------------
// WG wg owns output channels j in [wg*8, wg*8+8); holds the 40 W_lhh rows
// {g*1024 + wg*8 + jj} in f32 registers (160 VGPR/lane). One tree barrier per step.
__global__ __launch_bounds__(256, 1) void serial_chain(
    const float* __restrict__ Wl, const float* __restrict__ Wr,
    const float* __restrict__ pre, const int* __restrict__ plan,
    int* __restrict__ bar, float* __restrict__ hs, float* __restrict__ cs) {
  const int wg = blockIdx.x;
  const int tid = threadIdx.x;
  const int w = tid >> 6, l = tid & 63;
  const int nred = plan[P_CNT + 0];
  float wreg[RPW][16];
#pragma unroll
  for (int rr = 0; rr < RPW; ++rr) {
    const int ridx = w * RPW + rr;        // 0..39 ; ridx = g*8 + jj
    const int row = (ridx >> 3) * HDIM + wg * 8 + (ridx & 7);
    const float4* wp = (const float4*)(Wl + (long long)row * HDIM) + l * 4;
#pragma unroll
    for (int q = 0; q < 4; ++q) {
      float4 v = wp[q];
      wreg[rr][4 * q] = v.x; wreg[rr][4 * q + 1] = v.y;
      wreg[rr][4 * q + 2] = v.z; wreg[rr][4 * q + 3] = v.w;
    }
  }
  __shared__ float gsum[40];
  for (int r = 0; r < nred; ++r) {
    const int t = plan[P_TRED + r];
    const int ln = plan[P_LNODE + r];
    const int rn = plan[P_RNODE + r];
    const int fl = plan[P_FLAGS + r];
    float pv0 = 0.f, pv1 = 0.f, pv2 = 0.f, pv3 = 0.f, pv4 = 0.f, lc = 0.f, rc = 0.f;
    if (tid < 8) {
      const int j = wg * 8 + tid;
      const float* pr = pre + (long long)r * GDIM + j;
      pv0 = pr[0]; pv1 = pr[HDIM]; pv2 = pr[2 * HDIM]; pv3 = pr[3 * HDIM]; pv4 = pr[4 * HDIM];
      lc = cs[(long long)ln * HDIM + j];
      rc = cs[(long long)rn * HDIM + j];
    }
    float acc[RPW];
#pragma unroll
    for (int rr = 0; rr < RPW; ++rr) acc[rr] = 0.f;
    if (fl & 1) {  // left child is a reduce: W_lhh @ h[ln] from register weights
      const float4* hp = (const float4*)(hs + (long long)ln * HDIM) + l * 4;
      float hv[16];
#pragma unroll
      for (int q = 0; q < 4; ++q) {
        float4 v = hp[q];
        hv[4 * q] = v.x; hv[4 * q + 1] = v.y; hv[4 * q + 2] = v.z; hv[4 * q + 3] = v.w;
      }
#pragma unroll
      for (int rr = 0; rr < RPW; ++rr)
#pragma unroll
        for (int q = 0; q < 16; ++q) acc[rr] = fmaf(wreg[rr][q], hv[q], acc[rr]);
    }
    if (fl & 2) {  // right child is a reduce (never taken for comb data): stream W_rhh
      const float4* hp = (const float4*)(hs + (long long)rn * HDIM) + l * 4;
      float hv[16];
#pragma unroll
      for (int q = 0; q < 4; ++q) {
        float4 v = hp[q];
        hv[4 * q] = v.x; hv[4 * q + 1] = v.y; hv[4 * q + 2] = v.z; hv[4 * q + 3] = v.w;
      }
#pragma unroll
      for (int rr = 0; rr < RPW; ++rr) {
        const int ridx = w * RPW + rr;
        const int row = (ridx >> 3) * HDIM + wg * 8 + (ridx & 7);
        const float4* wp = (const float4*)(Wr + (long long)row * HDIM) + l * 4;
#pragma unroll
        for (int q = 0; q < 4; ++q) {
          float4 v = wp[q];
          acc[rr] = fmaf(v.x, hv[4 * q], acc[rr]);
          acc[rr] = fmaf(v.y, hv[4 * q + 1], acc[rr]);
          acc[rr] = fmaf(v.z, hv[4 * q + 2], acc[rr]);
          acc[rr] = fmaf(v.w, hv[4 * q + 3], acc[rr]);
        }
      }
    }
#pragma unroll
    for (int rr = 0; rr < RPW; ++rr) {
      float v = acc[rr];
      v += __shfl_xor(v, 32);
      v += __shfl_xor(v, 16);
      v += __shfl_xor(v, 8);
      v += __shfl_xor(v, 4);
      v += __shfl_xor(v, 2);
      v += __shfl_xor(v, 1);
      if (l == 0) gsum[w * RPW + rr] = v;
    }
    __syncthreads();
    if (tid < 8) {
      const int j = wg * 8 + tid;
      const float xi = pv0 + gsum[0 * 8 + tid];
      const float xlf = pv1 + gsum[1 * 8 + tid];
      const float xrf = pv2 + gsum[2 * 8 + tid];
      const float xg = pv3 + gsum[3 * 8 + tid];
      const float xo = pv4 + gsum[4 * 8 + tid];
      const float ii = sigf(xi), lf = sigf(xlf), rf = sigf(xrf);
      const float gv = tanh_f(xg), oo = sigf(xo);
      const float yc = lf * lc + rf * rc + ii * gv;
      const float yh = oo * tanh_f(yc);
      // agent-scope (LLC-direct) stores: per-WG slices are 32B, smaller than a
      // cache line, so L2-dirty stores would risk cross-XCD stale-line reads.
      __hip_atomic_store(&hs[(long long)t * HDIM + j], yh, __ATOMIC_RELAXED, __HIP_MEMORY_SCOPE_AGENT);
      __hip_atomic_store(&cs[(long long)t * HDIM + j], yc, __ATOMIC_RELAXED, __HIP_MEMORY_SCOPE_AGENT);
    }
    __syncthreads();
    if (tid == 0) {
      // tree barrier: 8 sub-counters of 16 -> root of 8 -> release epoch (monotonic)
      const int sub = wg >> 4;
      int old = __hip_atomic_fetch_add(&bar[64 + sub * 32], 1, __ATOMIC_ACQ_REL, __HIP_MEMORY_SCOPE_AGENT);
      if (old == (r + 1) * 16 - 1) {
        int ro = __hip_atomic_fetch_add(&bar[32], 1, __ATOMIC_ACQ_REL, __HIP_MEMORY_SCOPE_AGENT);
        if (ro == (r + 1) * 8 - 1) {
          __hip_atomic_store(&bar[0], r + 1, __ATOMIC_RELEASE, __HIP_MEMORY_SCOPE_AGENT);
        }
      }
      while (__hip_atomic_load(&bar[0], __ATOMIC_RELAXED, __HIP_MEMORY_SCOPE_AGENT) < r + 1) {
        __builtin_amdgcn_s_sleep(1);
      }
      __builtin_amdgcn_fence(__ATOMIC_ACQUIRE, "agent");
    }
    __syncthreads();
  }
}

__global__ void root_copy(float* __restrict__ out, const float* __restrict__ hs, int n_nodes) {
  int j = blockIdx.x * 256 + threadIdx.x;
  if (j < HDIM) out[j] = hs[(long long)(n_nodes - 1) * HDIM + j];
}

extern "C" void kernel_launch(void* const* d_in, const int* in_sizes, int n_in,
                              void* d_out, int out_size, void* d_ws, size_t ws_size,
                              hipStream_t stream) {
  const float* xs = (const float*)d_in[0];
  const int* ops = (const int*)d_in[1];
  const float* Wih = (const float*)d_in[2];
  const float* Wlhh = (const float*)d_in[3];
  const float* Wrhh = (const float*)d_in[4];
  const float* bih = (const float*)d_in[5];
  const float* blhh = (const float*)d_in[6];
  const float* brhh = (const float*)d_in[7];
  const int n_nodes = in_sizes[0] / HDIM;  // 4095

  char* ws = (char*)d_ws;
  float* wsf = (float*)d_ws;
  float* pre = (float*)(ws + PRE_OFF);
  float* leafg = (float*)(ws + LEAFG_OFF);
  unsigned short* xsbf = (unsigned short*)(ws + XSBF_OFF);
  unsigned short* wihb = (unsigned short*)(ws + WIH_OFF);
  unsigned short* wlhb = (unsigned short*)(ws + WLHH_OFF);
  unsigned short* wrhb = (unsigned short*)(ws + WRHH_OFF);
  unsigned short* hbf = (unsigned short*)(ws + HBF_OFF);
  float* b3 = (float*)(ws + B3_OFF);
  int* plan = (int*)(ws + PLAN_OFF);
  int* bar = (int*)(ws + BAR_OFF);

  float* out = (float*)d_out;
  float* hs = out + HDIM;
  float* cs = hs + (long long)n_nodes * HDIM;

  hipMemsetAsync(bar, 0, 4096, stream);
  hipLaunchKernelGGL(plan_kernel, dim3(1), dim3(256), 0, stream, ops, n_nodes, plan);
  hipLaunchKernelGGL(cvt_bf16_kernel, dim3(4096), dim3(256), 0, stream,
                     xs, xsbf, 4096 * HDIM, n_nodes * HDIM);
  hipLaunchKernelGGL(cvt_bf16_kernel, dim3(5120), dim3(256), 0, stream,
                     Wih, wihb, GDIM * HDIM, GDIM * HDIM);
  hipLaunchKernelGGL(cvt_bf16_kernel, dim3(5120), dim3(256), 0, stream,
                     Wlhh, wlhb, GDIM * HDIM, GDIM * HDIM);
  hipLaunchKernelGGL(cvt_bf16_kernel, dim3(5120), dim3(256), 0, stream,
                     Wrhh, wrhb, GDIM * HDIM, GDIM * HDIM);
  hipLaunchKernelGGL(b3_kernel, dim3(20), dim3(256), 0, stream, bih, blhh, brhh, b3);
  // G1: ih projection for all nodes, scattered to leafg / pre rows, +b3
  hipLaunchKernelGGL((gemm_bt<0, 0>), dim3(32, 40), dim3(256), 0, stream,
                     xsbf, wihb, (const int*)nullptr, plan + P_DEST1, wsf, b3, plan + P_CNT + 3);
  hipLaunchKernelGGL(leaf_cell, dim3((n_nodes + 1) / 2), dim3(256), 0, stream,
                     leafg, plan, hs, cs, hbf);
  // G2R: += W_rhh @ h[leaf right children] ; G2L: += W_lhh @ h[leaf left children]
  hipLaunchKernelGGL((gemm_bt<1, 1>), dim3(16, 40), dim3(256), 0, stream,
                     hbf, wrhb, plan + P_NODER, plan + P_DESTR, wsf, (const float*)nullptr, plan + P_CNT + 1);
  hipLaunchKernelGGL((gemm_bt<1, 1>), dim3(16, 40), dim3(256), 0, stream,
                     hbf, wlhb, plan + P_NODEL, plan + P_DESTL, wsf, (const float*)nullptr, plan + P_CNT + 2);
  hipLaunchKernelGGL(serial_chain, dim3(NWG_SER), dim3(256), 0, stream,
                     Wlhh, Wrhh, pre, plan, bar, hs, cs);
  hipLaunchKernelGGL(root_copy, dim3(4), dim3(256), 0, stream, out, hs, n_nodes);
}

// Round 3
// 9616.183 us; speedup vs baseline: 1.7890x; 1.7890x over previous
//
#include <hip/hip_runtime.h>
#include <hip/hip_bf16.h>
#include <stdint.h>

#define HDIM 1024
#define GDIM 5120
#define NWG_SER 128
#define RPW 10  // weight rows per wave in serial kernel (40 rows/WG / 4 waves)
#define NAN_U 0x7FC00000u

typedef __attribute__((ext_vector_type(8))) short v8s;
typedef __attribute__((ext_vector_type(4))) float v4f;

// ---------------- workspace layout (bytes) ----------------
constexpr long long PRE_OFF   = 0;                              // f32 [2048][5120] gate pre-sums for reduces
constexpr long long LEAFG_OFF = PRE_OFF   + 2048LL * 5120 * 4;  // f32 [2048][5120] leaf gates
constexpr long long DUMP_OFF  = LEAFG_OFF + 2048LL * 5120 * 4;  // f32 [8192] scratch dump row
constexpr long long XSBF_OFF  = DUMP_OFF  + 8192LL * 4;         // bf16 [4096][1024]
constexpr long long WIH_OFF   = XSBF_OFF  + 4096LL * 1024 * 2;  // bf16 [5120][1024]
constexpr long long WLHH_OFF  = WIH_OFF   + 5120LL * 1024 * 2;
constexpr long long WRHH_OFF  = WLHH_OFF  + 5120LL * 1024 * 2;
constexpr long long HBF_OFF   = WRHH_OFF  + 5120LL * 1024 * 2;  // bf16 [4096][1024] per-node h (GEMM input)
constexpr long long B3_OFF    = HBF_OFF   + 4096LL * 1024 * 2;  // f32 [5120]
constexpr long long PLAN_OFF  = B3_OFF    + 5120LL * 4;         // int [24576]
// total ~126.3 MiB

// plan array offsets (int units)
constexpr int P_TRED = 0, P_LNODE = 2048, P_RNODE = 4096, P_FLAGS = 6144,
              P_TLEAF = 8192, P_DEST1 = 10240, P_NODER = 14336, P_DESTR = 16384,
              P_NODEL = 18432, P_DESTL = 20480, P_CNT = 22528;
// counts: [0]=nred, [1]=activeR rows, [2]=activeL rows, [3]=n_nodes (G1 active rows)
// FLAGS packing: bit0 = left child is reduce; bit1 = right child is reduce;
//                bits2-3 = lidx (stack slot), bits4-5 = ridx, bits6-7 = pos.

// f32-element bases inside ws
constexpr int PRE_E   = 0;
constexpr int LEAFG_E = (int)(LEAFG_OFF / 4);
constexpr int DUMP_E  = (int)(DUMP_OFF / 4);

static __device__ __forceinline__ float sigf(float x) { return 1.0f / (1.0f + __expf(-x)); }
static __device__ __forceinline__ float tanh_f(float x) {
  if (x > 15.0f) return 1.0f;
  if (x < -15.0f) return -1.0f;
  float e = __expf(2.0f * x);
  return (e - 1.0f) / (e + 1.0f);
}
static __device__ __forceinline__ unsigned short f2bf(float x) {
  __hip_bfloat16 h = __float2bfloat16(x);
  union { __hip_bfloat16 h; unsigned short u; } cv;
  cv.h = h;
  return cv.u;
}

// ---------------- plan: simulate the stack, build scatter lists ----------------
__global__ void plan_kernel(const int* __restrict__ ops, int n_nodes, int* __restrict__ plan) {
  __shared__ int sops[4096];
  for (int i = threadIdx.x; i < n_nodes; i += 256) sops[i] = ops[i];
  __syncthreads();
  if (threadIdx.x != 0) return;
  int stack[4] = {0, 0, 0, 0};
  int ptr = 0, nred = 0, nleaf = 0, nR = 0, nL = 0;
  for (int t = 0; t < n_nodes; ++t) {
    int op = sops[t];
    if (op == 1) {
      int ridx = min(max(ptr - 1, 0), 3);
      int lidx = min(max(ptr - 2, 0), 3);
      int ln = stack[lidx], rn = stack[ridx];
      int r = nred++;
      plan[P_TRED + r] = t;
      plan[P_LNODE + r] = ln;
      plan[P_RNODE + r] = rn;
      int pos = min(max(ptr - 2, 0), 3);
      int lred = (sops[ln] == 1) ? 1 : 0;
      int rred = (sops[rn] == 1) ? 2 : 0;
      plan[P_FLAGS + r] = lred | rred | (lidx << 2) | (ridx << 4) | (pos << 6);
      plan[P_DEST1 + t] = PRE_E + r * GDIM;
      if (!rred) { plan[P_NODER + nR] = rn; plan[P_DESTR + nR] = PRE_E + r * GDIM; nR++; }
      if (!lred) { plan[P_NODEL + nL] = ln; plan[P_DESTL + nL] = PRE_E + r * GDIM; nL++; }
      stack[pos] = t;
      ptr = (ptr - 2) + 1;
    } else {
      int li = nleaf++;
      plan[P_TLEAF + li] = t;
      plan[P_DEST1 + t] = LEAFG_E + li * GDIM;
      stack[min(max(ptr, 0), 3)] = t;
      ptr = ptr + 1;
    }
  }
  for (int i = n_nodes; i < 4096; ++i) plan[P_DEST1 + i] = DUMP_E;
  for (int i = nR; i < 2048; ++i) { plan[P_NODER + i] = 0; plan[P_DESTR + i] = DUMP_E; }
  for (int i = nL; i < 2048; ++i) { plan[P_NODEL + i] = 0; plan[P_DESTL + i] = DUMP_E; }
  plan[P_CNT + 0] = nred;
  plan[P_CNT + 1] = nR;
  plan[P_CNT + 2] = nL;
  plan[P_CNT + 3] = n_nodes;
}

// ---------------- NaN-sentinel init for reduce-node h rows ----------------
__global__ void init_nan_kernel(const int* __restrict__ ops, int n_nodes,
                                unsigned int* __restrict__ hsu) {
  const int t = blockIdx.x;
  if (t >= n_nodes || ops[t] != 1) return;
  uint4 nv = make_uint4(NAN_U, NAN_U, NAN_U, NAN_U);
  *(uint4*)(hsu + (long long)t * HDIM + threadIdx.x * 4) = nv;
}

// ---------------- f32 -> bf16 convert (zero-pads beyond nsrc) ----------------
__global__ void cvt_bf16_kernel(const float* __restrict__ src, unsigned short* __restrict__ dst,
                                int ntotal, int nsrc) {
  int i = (blockIdx.x * 256 + threadIdx.x) * 4;
  if (i >= ntotal) return;
  float4 v = make_float4(0.f, 0.f, 0.f, 0.f);
  if (i < nsrc) v = *(const float4*)(src + i);
  ushort4 o;
  o.x = f2bf(v.x); o.y = f2bf(v.y); o.z = f2bf(v.z); o.w = f2bf(v.w);
  *(ushort4*)(dst + i) = o;
}

__global__ void b3_kernel(const float* __restrict__ a, const float* __restrict__ b,
                          const float* __restrict__ c, float* __restrict__ o) {
  int i = blockIdx.x * 256 + threadIdx.x;
  if (i < GDIM) o[i] = a[i] + b[i] + c[i];
}

// ---------------- NT MFMA GEMM with per-row scatter destinations ----------------
template <int GATHER, int ACCUM>
__global__ __launch_bounds__(256, 1) void gemm_bt(
    const unsigned short* __restrict__ A, const unsigned short* __restrict__ B,
    const int* __restrict__ gidx, const int* __restrict__ dest,
    float* __restrict__ wsf, const float* __restrict__ b3,
    const int* __restrict__ activeRows) {
  if ((int)blockIdx.x * 128 >= *activeRows) return;
  __shared__ unsigned short As[128 * 32];
  __shared__ unsigned short Bs[128 * 32];
  const int tid = threadIdx.x;
  const int w = tid >> 6, l = tid & 63;
  const int tm = blockIdx.x, tn = blockIdx.y;
  const int q0 = w * 2, q1 = w * 2 + 1;
  const int r0 = q0 * 16 + (l >> 2), r1 = q1 * 16 + (l >> 2);
  const int ck = (l & 3) * 8;
  int ga0 = tm * 128 + r0, ga1 = tm * 128 + r1;
  if (GATHER) { ga0 = gidx[ga0]; ga1 = gidx[ga1]; }
  const unsigned short* ap0 = A + (long long)ga0 * HDIM + ck;
  const unsigned short* ap1 = A + (long long)ga1 * HDIM + ck;
  const unsigned short* bp0 = B + (long long)(tn * 128 + r0) * HDIM + ck;
  const unsigned short* bp1 = B + (long long)(tn * 128 + r1) * HDIM + ck;
  uint4* asd0 = (uint4*)(As + q0 * 512) + l;
  uint4* asd1 = (uint4*)(As + q1 * 512) + l;
  uint4* bsd0 = (uint4*)(Bs + q0 * 512) + l;
  uint4* bsd1 = (uint4*)(Bs + q1 * 512) + l;
  const int wr = w >> 1, wc = w & 1;
  const int lrow = l & 15, lq = l >> 4;
  const unsigned short* Ard = As + (wr * 64 + lrow) * 32 + lq * 8;
  const unsigned short* Brd = Bs + (wc * 64 + lrow) * 32 + lq * 8;
  v4f acc[4][4];
#pragma unroll
  for (int m = 0; m < 4; ++m)
#pragma unroll
    for (int n = 0; n < 4; ++n) acc[m][n] = (v4f){0.f, 0.f, 0.f, 0.f};
  for (int kb = 0; kb < 32; ++kb) {
    const int ko = kb * 32;
    uint4 a0 = *(const uint4*)(ap0 + ko);
    uint4 a1 = *(const uint4*)(ap1 + ko);
    uint4 b0 = *(const uint4*)(bp0 + ko);
    uint4 b1 = *(const uint4*)(bp1 + ko);
    __syncthreads();
    *asd0 = a0; *asd1 = a1; *bsd0 = b0; *bsd1 = b1;
    __syncthreads();
    v8s af[4], bfr[4];
#pragma unroll
    for (int m = 0; m < 4; ++m) af[m] = *(const v8s*)(Ard + m * 512);
#pragma unroll
    for (int n = 0; n < 4; ++n) bfr[n] = *(const v8s*)(Brd + n * 512);
#pragma unroll
    for (int m = 0; m < 4; ++m)
#pragma unroll
      for (int n = 0; n < 4; ++n)
        acc[m][n] = __builtin_amdgcn_mfma_f32_16x16x32_bf16(af[m], bfr[n], acc[m][n], 0, 0, 0);
  }
#pragma unroll
  for (int m = 0; m < 4; ++m) {
#pragma unroll
    for (int jj = 0; jj < 4; ++jj) {
      const int arow = tm * 128 + wr * 64 + m * 16 + lq * 4 + jj;
      const int doff = dest[arow];
#pragma unroll
      for (int n = 0; n < 4; ++n) {
        const int col = tn * 128 + wc * 64 + n * 16 + lrow;
        float v = acc[m][n][jj];
        if (ACCUM) wsf[doff + col] += v;
        else wsf[doff + col] = v + b3[col];
      }
    }
  }
}

// ---------------- leaf (shift) cell: gates -> h,c with zero hidden state ----------------
__global__ void leaf_cell(const float* __restrict__ leafg, const int* __restrict__ plan,
                          float* __restrict__ hs, float* __restrict__ cs,
                          unsigned short* __restrict__ hbf) {
  const int li = blockIdx.x;
  const int j = threadIdx.x * 4;
  const float* row = leafg + (long long)li * GDIM;
  float4 gi = *(const float4*)(row + j);
  float4 gg = *(const float4*)(row + 3 * HDIM + j);
  float4 go = *(const float4*)(row + 4 * HDIM + j);
  const int t = plan[P_TLEAF + li];
  float4 yc, yh;
  yc.x = sigf(gi.x) * tanh_f(gg.x); yc.y = sigf(gi.y) * tanh_f(gg.y);
  yc.z = sigf(gi.z) * tanh_f(gg.z); yc.w = sigf(gi.w) * tanh_f(gg.w);
  yh.x = sigf(go.x) * tanh_f(yc.x); yh.y = sigf(go.y) * tanh_f(yc.y);
  yh.z = sigf(go.z) * tanh_f(yc.z); yh.w = sigf(go.w) * tanh_f(yc.w);
  *(float4*)(hs + (long long)t * HDIM + j) = yh;
  *(float4*)(cs + (long long)t * HDIM + j) = yc;
  ushort4 hb;
  hb.x = f2bf(yh.x); hb.y = f2bf(yh.y); hb.z = f2bf(yh.z); hb.w = f2bf(yh.w);
  *(ushort4*)(hbf + (long long)t * HDIM + j) = hb;
}

// ---------------- serial reduce chain: NaN-sentinel dataflow sync ----------------
// WG wg owns channels j in [wg*8, wg*8+8); 40 W_lhh rows in f32 registers,
// lane l holds columns {q*64+l}. Sync: h words themselves (NaN = not ready);
// relaxed agent-scope loads/stores, no fences, no RMW barrier.
__global__ __launch_bounds__(256, 1) void serial_chain(
    const float* __restrict__ Wl, const float* __restrict__ Wr,
    const float* __restrict__ pre, const int* __restrict__ plan,
    float* __restrict__ hs, float* __restrict__ cs) {
  const int wg = blockIdx.x;
  const int tid = threadIdx.x;
  const int w = tid >> 6, l = tid & 63;
  __shared__ int s_t[2048], s_ln[2048], s_rn[2048], s_fl[2048];
  __shared__ float gsum[40];
  __shared__ float c_stack[4][8];
  const int nred = plan[P_CNT + 0];
  for (int i = tid; i < nred; i += 256) {
    s_t[i] = plan[P_TRED + i];
    s_ln[i] = plan[P_LNODE + i];
    s_rn[i] = plan[P_RNODE + i];
    s_fl[i] = plan[P_FLAGS + i];
  }
  float wreg[RPW][16];
#pragma unroll
  for (int rr = 0; rr < RPW; ++rr) {
    const int ridx = w * RPW + rr;  // ridx = g*8 + jj
    const long long row = (long long)((ridx >> 3) * HDIM + wg * 8 + (ridx & 7)) * HDIM;
#pragma unroll
    for (int q = 0; q < 16; ++q) wreg[rr][q] = Wl[row + q * 64 + l];
  }
  float pv0 = 0.f, pv1 = 0.f, pv2 = 0.f, pv3 = 0.f, pv4 = 0.f;
  if (tid < 8) {
    const float* pr = pre + wg * 8 + tid;
    pv0 = pr[0]; pv1 = pr[HDIM]; pv2 = pr[2 * HDIM]; pv3 = pr[3 * HDIM]; pv4 = pr[4 * HDIM];
  }
  __syncthreads();
  for (int r = 0; r < nred; ++r) {
    const int t = s_t[r], ln = s_ln[r], rn = s_rn[r], fl = s_fl[r];
    // early-issue child c loads (leaf children: plain global, overlaps the poll)
    float lc = 0.f, rc = 0.f;
    if (tid < 8) {
      const int jj = wg * 8 + tid;
      if (fl & 1) lc = c_stack[(fl >> 2) & 3][tid];
      else        lc = cs[(long long)ln * HDIM + jj];
      if (fl & 2) rc = c_stack[(fl >> 4) & 3][tid];
      else        rc = cs[(long long)rn * HDIM + jj];
    }
    // h acquisition: poll NaN sentinel if left child is a reduce
    float hv[16];
    {
      const float* hrow = hs + (long long)ln * HDIM;
      if (fl & 1) {
        bool ready = false;
        while (!ready) {
          ready = true;
#pragma unroll
          for (int q = 0; q < 16; ++q) {
            unsigned int u = __hip_atomic_load((unsigned int*)(hrow + q * 64 + l),
                                               __ATOMIC_RELAXED, __HIP_MEMORY_SCOPE_AGENT);
            ready = ready && (u != NAN_U);
            hv[q] = __uint_as_float(u);
          }
        }
      } else {
#pragma unroll
        for (int q = 0; q < 16; ++q) hv[q] = hrow[q * 64 + l];
      }
    }
    float acc[RPW];
#pragma unroll
    for (int rr = 0; rr < RPW; ++rr) acc[rr] = 0.f;
#pragma unroll
    for (int rr = 0; rr < RPW; ++rr)
#pragma unroll
      for (int q = 0; q < 16; ++q) acc[rr] = fmaf(wreg[rr][q], hv[q], acc[rr]);
    if (fl & 2) {  // right child is a reduce (never for comb data): stream W_rhh
      float hv2[16];
      const float* hrow2 = hs + (long long)rn * HDIM;
      bool ready = false;
      while (!ready) {
        ready = true;
#pragma unroll
        for (int q = 0; q < 16; ++q) {
          unsigned int u = __hip_atomic_load((unsigned int*)(hrow2 + q * 64 + l),
                                             __ATOMIC_RELAXED, __HIP_MEMORY_SCOPE_AGENT);
          ready = ready && (u != NAN_U);
          hv2[q] = __uint_as_float(u);
        }
      }
#pragma unroll
      for (int rr = 0; rr < RPW; ++rr) {
        const int ridx = w * RPW + rr;
        const long long row = (long long)((ridx >> 3) * HDIM + wg * 8 + (ridx & 7)) * HDIM;
#pragma unroll
        for (int q = 0; q < 16; ++q) acc[rr] = fmaf(Wr[row + q * 64 + l], hv2[q], acc[rr]);
      }
    }
#pragma unroll
    for (int rr = 0; rr < RPW; ++rr) {
      float v = acc[rr];
      v += __shfl_xor(v, 32); v += __shfl_xor(v, 16); v += __shfl_xor(v, 8);
      v += __shfl_xor(v, 4);  v += __shfl_xor(v, 2);  v += __shfl_xor(v, 1);
      if (l == 0) gsum[w * RPW + rr] = v;
    }
    __syncthreads();
    if (tid < 8) {
      const int jj = wg * 8 + tid;
      const float xi  = pv0 + gsum[0 * 8 + tid];
      const float xlf = pv1 + gsum[1 * 8 + tid];
      const float xrf = pv2 + gsum[2 * 8 + tid];
      const float xg  = pv3 + gsum[3 * 8 + tid];
      const float xo  = pv4 + gsum[4 * 8 + tid];
      const float ii = sigf(xi), lf = sigf(xlf), rf = sigf(xrf);
      const float gv = tanh_f(xg), oo = sigf(xo);
      const float yc = lf * lc + rf * rc + ii * gv;
      const float yh = oo * tanh_f(yc);
      cs[(long long)t * HDIM + jj] = yc;           // intra-WG + validation only
      c_stack[(fl >> 6) & 3][tid] = yc;            // local stack copy
      __hip_atomic_store((unsigned int*)&hs[(long long)t * HDIM + jj], __float_as_uint(yh),
                         __ATOMIC_RELAXED, __HIP_MEMORY_SCOPE_AGENT);
      if (r + 1 < nred) {                          // prefetch next step's pre slice
        const float* pr = pre + (long long)(r + 1) * GDIM + jj;
        pv0 = pr[0]; pv1 = pr[HDIM]; pv2 = pr[2 * HDIM]; pv3 = pr[3 * HDIM]; pv4 = pr[4 * HDIM];
      }
    }
    __syncthreads();
  }
}

__global__ void root_copy(float* __restrict__ out, const float* __restrict__ hs, int n_nodes) {
  int j = blockIdx.x * 256 + threadIdx.x;
  if (j < HDIM) out[j] = hs[(long long)(n_nodes - 1) * HDIM + j];
}

extern "C" void kernel_launch(void* const* d_in, const int* in_sizes, int n_in,
                              void* d_out, int out_size, void* d_ws, size_t ws_size,
                              hipStream_t stream) {
  const float* xs = (const float*)d_in[0];
  const int* ops = (const int*)d_in[1];
  const float* Wih = (const float*)d_in[2];
  const float* Wlhh = (const float*)d_in[3];
  const float* Wrhh = (const float*)d_in[4];
  const float* bih = (const float*)d_in[5];
  const float* blhh = (const float*)d_in[6];
  const float* brhh = (const float*)d_in[7];
  const int n_nodes = in_sizes[0] / HDIM;  // 4095

  char* ws = (char*)d_ws;
  float* wsf = (float*)d_ws;
  float* pre = (float*)(ws + PRE_OFF);
  float* leafg = (float*)(ws + LEAFG_OFF);
  unsigned short* xsbf = (unsigned short*)(ws + XSBF_OFF);
  unsigned short* wihb = (unsigned short*)(ws + WIH_OFF);
  unsigned short* wlhb = (unsigned short*)(ws + WLHH_OFF);
  unsigned short* wrhb = (unsigned short*)(ws + WRHH_OFF);
  unsigned short* hbf = (unsigned short*)(ws + HBF_OFF);
  float* b3 = (float*)(ws + B3_OFF);
  int* plan = (int*)(ws + PLAN_OFF);

  float* out = (float*)d_out;
  float* hs = out + HDIM;
  float* cs = hs + (long long)n_nodes * HDIM;

  hipLaunchKernelGGL(plan_kernel, dim3(1), dim3(256), 0, stream, ops, n_nodes, plan);
  hipLaunchKernelGGL(init_nan_kernel, dim3(n_nodes), dim3(256), 0, stream,
                     ops, n_nodes, (unsigned int*)hs);
  hipLaunchKernelGGL(cvt_bf16_kernel, dim3(4096), dim3(256), 0, stream,
                     xs, xsbf, 4096 * HDIM, n_nodes * HDIM);
  hipLaunchKernelGGL(cvt_bf16_kernel, dim3(5120), dim3(256), 0, stream,
                     Wih, wihb, GDIM * HDIM, GDIM * HDIM);
  hipLaunchKernelGGL(cvt_bf16_kernel, dim3(5120), dim3(256), 0, stream,
                     Wlhh, wlhb, GDIM * HDIM, GDIM * HDIM);
  hipLaunchKernelGGL(cvt_bf16_kernel, dim3(5120), dim3(256), 0, stream,
                     Wrhh, wrhb, GDIM * HDIM, GDIM * HDIM);
  hipLaunchKernelGGL(b3_kernel, dim3(20), dim3(256), 0, stream, bih, blhh, brhh, b3);
  // G1: ih projection for all nodes, scattered to leafg / pre rows, +b3
  hipLaunchKernelGGL((gemm_bt<0, 0>), dim3(32, 40), dim3(256), 0, stream,
                     xsbf, wihb, (const int*)nullptr, plan + P_DEST1, wsf, b3, plan + P_CNT + 3);
  hipLaunchKernelGGL(leaf_cell, dim3((n_nodes + 1) / 2), dim3(256), 0, stream,
                     leafg, plan, hs, cs, hbf);
  // G2R: += W_rhh @ h[leaf right children] ; G2L: += W_lhh @ h[leaf left children]
  hipLaunchKernelGGL((gemm_bt<1, 1>), dim3(16, 40), dim3(256), 0, stream,
                     hbf, wrhb, plan + P_NODER, plan + P_DESTR, wsf, (const float*)nullptr, plan + P_CNT + 1);
  hipLaunchKernelGGL((gemm_bt<1, 1>), dim3(16, 40), dim3(256), 0, stream,
                     hbf, wlhb, plan + P_NODEL, plan + P_DESTL, wsf, (const float*)nullptr, plan + P_CNT + 2);
  hipLaunchKernelGGL(serial_chain, dim3(NWG_SER), dim3(256), 0, stream,
                     Wlhh, Wrhh, pre, plan, hs, cs);
  hipLaunchKernelGGL(root_copy, dim3(4), dim3(256), 0, stream, out, hs, n_nodes);
}